// Round 1
// baseline (441.320 us; speedup 1.0000x reference)
//
#include <hip/hip_runtime.h>
#include <hip/hip_bf16.h>
#include <math.h>

// B=8, P=2048, Q=1024, H=1024
// 1. convert k,q,Wk,Wq fp32 -> fp16 (single fused launch)
// 2. pkey16 = relu(k @ Wk^T)   MFMA f16 (parked in d_out ctx region)
// 3. qkey16 = relu(q @ Wq^T)   MFMA f16
// 4. scores = pkey @ qkey^T    MFMA f16, fp32 -> alphas slice of d_out
// 5. qT16 = transpose(q) fp16
// 6. softmax rows in place + fp16 alphas copy
// 7. ctx = alphas16 @ qT16^T   MFMA f16, fp32 -> d_out base
//
// GEMM: m97 structure (measured 874-912 TF on gfx950): 128x128 tile, BK=32,
// 256 thr = 4 waves in 2x2, each wave owns a 64x64 sub-tile (4x4 frags of
// 16x16x32 f16 MFMA). 16 MFMA : 8 ds_read_b128 per K-step per wave.
// Staging via global_load_lds width=16 (4 issues/thread/K-step).
// NOTE: no __launch_bounds__ min-waves — 4x4 acc needs ~164 VGPR (3 waves/
// SIMD); forcing 4 waves/SIMD (128 VGPR) strangles the register allocator
// (previous session's "R2" regression).
// 1D grid decoded M-fastest so consecutive blocks share the B tile (L2 reuse).

typedef _Float16 v8h __attribute__((ext_vector_type(8)));
typedef _Float16 v4h __attribute__((ext_vector_type(4)));
typedef float v4f __attribute__((ext_vector_type(4)));

#define AS1C(p) ((const __attribute__((address_space(1))) void*)(p))
#define AS3(p)  ((__attribute__((address_space(3))) void*)(p))

// ---------------------------------------------------------------------------
// NT MFMA GEMM: C[m,n] = sum_k A[m,k]*B[n,k], A:[M,K] B:[N,K] row-major f16.
__global__ __launch_bounds__(256) void gemm_nt_f16(
    const _Float16* __restrict__ A, const _Float16* __restrict__ B,
    float* __restrict__ Cf, _Float16* __restrict__ Ch,
    int N, int K, int Mtiles, int Ntiles,
    long long sA, long long sB, long long sC, int relu)
{
  __shared__ _Float16 As[128 * 32];   // 8 KB
  __shared__ _Float16 Bs[128 * 32];   // 8 KB

  // M-fastest decode: consecutive blocks share the B (N) tile.
  const int bid = blockIdx.x;
  const int mt  = bid % Mtiles;
  const int nt  = (bid / Mtiles) % Ntiles;
  const int bz  = bid / (Mtiles * Ntiles);

  A += (long long)bz * sA;
  B += (long long)bz * sB;

  const int m0 = mt * 128;
  const int n0 = nt * 128;
  const int t  = threadIdx.x;
  const int l  = t & 63;
  const int w  = t >> 6;
  const int wm = (w >> 1) * 64;   // wave m offset (0 or 64)
  const int wn = (w & 1) * 64;    // wave n offset (0 or 64)
  const int fr = l & 15;
  const int fq = l >> 4;

  const int srow = t >> 2;          // 0..63
  const int scol = (t & 3) << 3;    // 0,8,16,24

  v4f acc[4][4];
#pragma unroll
  for (int i = 0; i < 4; ++i)
#pragma unroll
    for (int j = 0; j < 4; ++j)
      acc[i][j] = (v4f){0.f, 0.f, 0.f, 0.f};

  const _Float16* Ap = A + (long long)(m0 + srow) * K + scol;
  const _Float16* Bp = B + (long long)(n0 + srow) * K + scol;

  for (int k0 = 0; k0 < K; k0 += 32) {
    // Stage A[128x32] and B[128x32]: 16B/lane, LDS dest = wave-uniform + lane*16.
    __builtin_amdgcn_global_load_lds(AS1C(Ap + k0),          AS3(As + t * 8),        16, 0, 0);
    __builtin_amdgcn_global_load_lds(AS1C(Ap + 64 * K + k0), AS3(As + 2048 + t * 8), 16, 0, 0);
    __builtin_amdgcn_global_load_lds(AS1C(Bp + k0),          AS3(Bs + t * 8),        16, 0, 0);
    __builtin_amdgcn_global_load_lds(AS1C(Bp + 64 * K + k0), AS3(Bs + 2048 + t * 8), 16, 0, 0);
    __syncthreads();

    v8h a[4], b[4];
#pragma unroll
    for (int i = 0; i < 4; ++i)
      a[i] = *(const v8h*)&As[(wm + i * 16 + fr) * 32 + fq * 8];
#pragma unroll
    for (int j = 0; j < 4; ++j)
      b[j] = *(const v8h*)&Bs[(wn + j * 16 + fr) * 32 + fq * 8];

#pragma unroll
    for (int i = 0; i < 4; ++i)
#pragma unroll
      for (int j = 0; j < 4; ++j)
        acc[i][j] = __builtin_amdgcn_mfma_f32_16x16x32_f16(a[i], b[j], acc[i][j], 0, 0, 0);

    __syncthreads();
  }

  float* Cfb = Cf ? Cf + (long long)bz * sC : nullptr;
  _Float16* Chb = Ch ? Ch + (long long)bz * sC : nullptr;
#pragma unroll
  for (int i = 0; i < 4; ++i) {
#pragma unroll
    for (int j = 0; j < 4; ++j) {
#pragma unroll
      for (int r = 0; r < 4; ++r) {
        const int row = m0 + wm + i * 16 + fq * 4 + r;
        const int col = n0 + wn + j * 16 + fr;
        float v = acc[i][j][r];
        if (relu) v = fmaxf(v, 0.f);
        if (Cfb) Cfb[(long long)row * N + col] = v;
        if (Chb) Chb[(long long)row * N + col] = (_Float16)v;
      }
    }
  }
}

// ---------------------------------------------------------------------------
// Fused fp32->fp16 conversion of all four inputs in one launch.
// Each block handles 1024 elements of one of the arrays.
__global__ __launch_bounds__(256) void convert_all_kernel(
    const float* __restrict__ s0, _Float16* __restrict__ d0, int b0,  // k
    const float* __restrict__ s1, _Float16* __restrict__ d1, int b1,  // q
    const float* __restrict__ s2, _Float16* __restrict__ d2, int b2,  // Wk
    const float* __restrict__ s3, _Float16* __restrict__ d3)          // Wq
{
  int blk = blockIdx.x;
  const float* src;
  _Float16* dst;
  if (blk < b0)           { src = s0; dst = d0; }
  else if (blk < b0 + b1) { src = s1; dst = d1; blk -= b0; }
  else if (blk < b0 + b1 + b2) { src = s2; dst = d2; blk -= b0 + b1; }
  else                    { src = s3; dst = d3; blk -= b0 + b1 + b2; }
  const long long i = ((long long)blk * 256 + threadIdx.x) * 4;
  const float4 v = *(const float4*)(src + i);
  v4h o = {(_Float16)v.x, (_Float16)v.y, (_Float16)v.z, (_Float16)v.w};
  *(v4h*)(dst + i) = o;
}

// q [B,Q,H] fp32 -> qT [B,H,Q] fp16, 64x64 tiles
__global__ __launch_bounds__(256) void transpose_f16_kernel(
    const float* __restrict__ q, _Float16* __restrict__ qT, int Q, int H)
{
  __shared__ float tile[64][65];
  const float* qb = q + (long long)blockIdx.z * Q * H;
  _Float16* qTb = qT + (long long)blockIdx.z * H * Q;
  const int q0 = blockIdx.x * 64, h0 = blockIdx.y * 64;
  const int t = threadIdx.x;
  const int tr = t >> 4, tc = (t & 15) << 2;
#pragma unroll
  for (int i = 0; i < 4; ++i) {
    const float4 v = *(const float4*)(qb + (long long)(q0 + tr + i * 16) * H + h0 + tc);
    tile[tr + i * 16][tc + 0] = v.x;
    tile[tr + i * 16][tc + 1] = v.y;
    tile[tr + i * 16][tc + 2] = v.z;
    tile[tr + i * 16][tc + 3] = v.w;
  }
  __syncthreads();
#pragma unroll
  for (int i = 0; i < 4; ++i) {
    const int hl = tr + i * 16;
    const int ql = tc;
    v4h o = {(_Float16)tile[ql + 0][hl], (_Float16)tile[ql + 1][hl],
             (_Float16)tile[ql + 2][hl], (_Float16)tile[ql + 3][hl]};
    *(v4h*)(qTb + (long long)(h0 + hl) * Q + q0 + ql) = o;
  }
}

// softmax rows of S [B*P, Q] fp32 in place; also write fp16 copy
__global__ __launch_bounds__(256) void softmax_rows_kernel(
    float* __restrict__ S, _Float16* __restrict__ S16,
    const unsigned char* __restrict__ qmask, int Q, int P)
{
  const long long row = blockIdx.x;       // b*P + p
  const int b = (int)(row / P);
  float* s = S + row * (long long)Q;
  const unsigned char* msk = qmask + (long long)b * Q;
  const int t = threadIdx.x;
  float4 v = *(const float4*)(s + (t << 2));
  float vals[4] = {v.x, v.y, v.z, v.w};
#pragma unroll
  for (int j = 0; j < 4; ++j)
    if (msk[(t << 2) + j]) vals[j] = -INFINITY;

  __shared__ float red[8];
  const int wid = t >> 6, lid = t & 63;

  float mx = fmaxf(fmaxf(vals[0], vals[1]), fmaxf(vals[2], vals[3]));
#pragma unroll
  for (int o = 32; o > 0; o >>= 1) mx = fmaxf(mx, __shfl_xor(mx, o, 64));
  if (lid == 0) red[wid] = mx;
  __syncthreads();
  mx = fmaxf(fmaxf(red[0], red[1]), fmaxf(red[2], red[3]));

  float e[4];
  float sum = 0.f;
#pragma unroll
  for (int j = 0; j < 4; ++j) { e[j] = __expf(vals[j] - mx); sum += e[j]; }
#pragma unroll
  for (int o = 32; o > 0; o >>= 1) sum += __shfl_xor(sum, o, 64);
  __syncthreads();
  if (lid == 0) red[4 + wid] = sum;
  __syncthreads();
  sum = red[4] + red[5] + red[6] + red[7];
  const float inv = 1.f / sum;

  float4 o;
  o.x = e[0] * inv; o.y = e[1] * inv; o.z = e[2] * inv; o.w = e[3] * inv;
  *(float4*)(s + (t << 2)) = o;
  v4h oh = {(_Float16)o.x, (_Float16)o.y, (_Float16)o.z, (_Float16)o.w};
  *(v4h*)(S16 + row * (long long)Q + (t << 2)) = oh;
}

// ---------------------------------------------------------------------------
extern "C" void kernel_launch(void* const* d_in, const int* in_sizes, int n_in,
                              void* d_out, int out_size, void* d_ws, size_t ws_size,
                              hipStream_t stream)
{
  const int B = 8, P = 2048, Q = 1024, H = 1024;
  const float* k  = (const float*)d_in[0];
  const float* q  = (const float*)d_in[1];
  const unsigned char* qmask = (const unsigned char*)d_in[2];
  const float* Wk = (const float*)d_in[3];
  const float* Wq = (const float*)d_in[4];

  float* ctx    = (float*)d_out;                  // [B,P,H] fp32
  float* alphas = ctx + (size_t)B * P * H;        // [B,P,Q] fp32

  _Float16* pkey16 = (_Float16*)d_out;            // parked in ctx region

  char* wsb = (char*)d_ws;
  _Float16* qkey16   = (_Float16*)(wsb);                        // 16.78 MB
  _Float16* k16      = (_Float16*)(wsb + 16777216);             // 33.55 MB
  _Float16* alphas16 = k16;                                     // k16 dead after proj_k
  _Float16* q16      = (_Float16*)(wsb + 16777216 + 33554432);  // 16.78 MB
  _Float16* qT16     = q16;                                     // q16 dead after proj_q
  _Float16* Wk16     = (_Float16*)(wsb + 67108864);
  _Float16* Wq16     = (_Float16*)(wsb + 69206016);

  const long long nK = (long long)B * P * H;   // 16.78M
  const long long nQ = (long long)B * Q * H;   // 8.39M
  const long long nW = (long long)H * H;       // 1.05M

  // 1. fused converts
  const int bK = (int)(nK / 1024), bQ = (int)(nQ / 1024), bW = (int)(nW / 1024);
  convert_all_kernel<<<bK + bQ + 2 * bW, 256, 0, stream>>>(
      k, k16, bK, q, q16, bQ, Wk, Wk16, bW, Wq, Wq16);

  // 2. pkey16 = relu(k16 @ Wk16^T)  [16384 x 1024], tiles 128x128
  gemm_nt_f16<<<(16384 / 128) * (1024 / 128), 256, 0, stream>>>(
      k16, Wk16, nullptr, pkey16, H, H, 16384 / 128, 1024 / 128, 0LL, 0LL, 0LL, 1);
  // 3. qkey16 = relu(q16 @ Wq16^T)  [8192 x 1024]
  gemm_nt_f16<<<(8192 / 128) * (1024 / 128), 256, 0, stream>>>(
      q16, Wq16, nullptr, qkey16, H, H, 8192 / 128, 1024 / 128, 0LL, 0LL, 0LL, 1);
  // 4. scores = pkey16 @ qkey16^T (batched) -> alphas slice fp32
  gemm_nt_f16<<<(P / 128) * (Q / 128) * B, 256, 0, stream>>>(
      pkey16, qkey16, alphas, nullptr, Q, H, P / 128, Q / 128,
      (long long)P * H, (long long)Q * H, (long long)P * Q, 0);
  // 5. qT16 = q^T fp16 (overwrites q16)
  transpose_f16_kernel<<<dim3(Q / 64, H / 64, B), 256, 0, stream>>>(q, qT16, Q, H);
  // 6. softmax in place + fp16 copy (overwrites k16)
  softmax_rows_kernel<<<B * P, 256, 0, stream>>>(alphas, alphas16, qmask, Q, P);
  // 7. ctx = alphas16 @ qT16^T (batched NT) -> d_out base
  gemm_nt_f16<<<(P / 128) * (H / 128) * B, 256, 0, stream>>>(
      alphas16, qT16, ctx, nullptr, H, Q, P / 128, H / 128,
      (long long)P * Q, (long long)H * Q, (long long)P * H, 0);
}

// Round 2
// 394.909 us; speedup vs baseline: 1.1175x; 1.1175x over previous
//
#include <hip/hip_runtime.h>
#include <hip/hip_bf16.h>
#include <math.h>

// B=8, P=2048, Q=1024, H=1024
// 1. convert k,q,Wk,Wq fp32 -> fp16 (single fused launch)
// 2. pkey16 = relu(k @ Wk^T)   MFMA f16 (parked in d_out ctx region)
// 3. qkey16 = relu(q @ Wq^T)   MFMA f16
// 4. scores = pkey @ qkey^T    MFMA f16, fp32 -> alphas slice of d_out
// 5. qT16 = transpose(q) fp16
// 6. softmax rows in place + fp16 alphas copy
// 7. ctx = alphas16 @ qT16^T   MFMA f16, fp32 -> d_out base
//
// GEMM: deep-pipelined 256x256 tile, BK=32, 512 thr = 8 waves (2M x 4N),
// per-wave 128x64 output (acc[8][4] of 16x16 f16 MFMA frags).
// 4 LDS buffers x 32KB = 128KB (dynamic), 3-deep prefetch:
//   per K-tile t: s_waitcnt vmcnt(8)  (own 4 loads of tile t landed;
//                 t+1,t+2 = 8 loads stay IN FLIGHT across the barrier)
//                 -> one raw s_barrier -> stage t+3 (into buffer whose
//                 reads finished last iteration, safe: all waves passed
//                 this barrier after consuming it) -> 12 ds_read_b128 +
//                 32 MFMA under s_setprio(1).
// Counted vmcnt (T4) + raw barrier + setprio (T5) per the T-catalog; the
// old 2-barrier __syncthreads loop drained vmcnt(0) every K-step (the
// documented ~900TF-structure stall, worse at K=1024).
// BK=32 => 64B LDS rows => frag reads hit all 32 banks at 2 lanes/bank
// (free, m136) -- no swizzle needed (the 16-way hazard is a BK=64 artifact).
// Tail: vmcnt(4) at NT-2, vmcnt(0) at NT-1. NT=K/32=32 >= 4.
// 1 block/CU (128KB LDS, ~220 VGPR): pipeline replaces TLP by design.

typedef _Float16 v8h __attribute__((ext_vector_type(8)));
typedef _Float16 v4h __attribute__((ext_vector_type(4)));
typedef float v4f __attribute__((ext_vector_type(4)));

#define AS1C(p) ((const __attribute__((address_space(1))) void*)(p))
#define AS3(p)  ((__attribute__((address_space(3))) void*)(p))

// ---------------------------------------------------------------------------
// NT MFMA GEMM: C[m,n] = sum_k A[m,k]*B[n,k], A:[M,K] B:[N,K] row-major f16.
// Grid must be a multiple of 8 (XCD swizzle); M%256==0, N%256==0, K%32==0, K>=128.
__global__ __launch_bounds__(512) void gemm_nt_f16_256(
    const _Float16* __restrict__ A, const _Float16* __restrict__ B,
    float* __restrict__ Cf, _Float16* __restrict__ Ch,
    int N, int K, int Mtiles, int Ntiles,
    long long sA, long long sB, long long sC, int relu)
{
  extern __shared__ _Float16 lds[];   // 4 bufs x (As 8192 | Bs 8192) halves = 128KB

  // XCD-aware swizzle (nwg % 8 == 0 for all our grids), then M-fastest decode:
  // each XCD gets a contiguous chunk of consecutive mt (shared B panel in L2).
  const int nwg = gridDim.x;
  const int cpx = nwg >> 3;
  const int bid = (blockIdx.x & 7) * cpx + (blockIdx.x >> 3);
  const int mt  = bid % Mtiles;
  const int nt  = (bid / Mtiles) % Ntiles;
  const int bz  = bid / (Mtiles * Ntiles);

  A += (long long)bz * sA;
  B += (long long)bz * sB;

  const int m0 = mt * 256;
  const int n0 = nt * 256;
  const int t  = threadIdx.x;       // 0..511
  const int l  = t & 63;
  const int w  = t >> 6;            // 0..7
  const int wm = (w >> 2) * 128;    // wave m offset: 0 or 128
  const int wn = (w & 3) * 64;      // wave n offset: 0,64,128,192
  const int fr = l & 15;
  const int fq = l >> 4;

  // staging: thread t covers LDS halves [t*8, t*8+8) of each 8KB round.
  // round layout: As rows 0..127 | As rows 128..255 | Bs 0..127 | Bs 128..255
  const int tr = t >> 2;            // 0..127 (row within round)
  const int tc = (t & 3) * 8;       // 0,8,16,24 (col halves within BK=32)

  const _Float16* A0 = A + (long long)(m0 + tr) * K + tc;
  const _Float16* A1 = A + (long long)(m0 + 128 + tr) * K + tc;
  const _Float16* B0 = B + (long long)(n0 + tr) * K + tc;
  const _Float16* B1 = B + (long long)(n0 + 128 + tr) * K + tc;

  v4f acc[8][4];
#pragma unroll
  for (int i = 0; i < 8; ++i)
#pragma unroll
    for (int j = 0; j < 4; ++j)
      acc[i][j] = (v4f){0.f, 0.f, 0.f, 0.f};

  const int NT = K >> 5;            // K-tiles of 32

#define STAGE(kt) do {                                                              \
    _Float16* s_ = lds + (((kt) & 3) << 14);                                        \
    const int ko_ = (kt) << 5;                                                      \
    __builtin_amdgcn_global_load_lds(AS1C(A0 + ko_), AS3(s_ +         t * 8), 16, 0, 0); \
    __builtin_amdgcn_global_load_lds(AS1C(A1 + ko_), AS3(s_ +  4096 + t * 8), 16, 0, 0); \
    __builtin_amdgcn_global_load_lds(AS1C(B0 + ko_), AS3(s_ +  8192 + t * 8), 16, 0, 0); \
    __builtin_amdgcn_global_load_lds(AS1C(B1 + ko_), AS3(s_ + 12288 + t * 8), 16, 0, 0); \
  } while (0)

  // Prologue: 3-deep prefetch (12 loads in flight).
  STAGE(0);
  STAGE(1);
  STAGE(2);

  for (int kt = 0; kt < NT; ++kt) {
    // Wait until own loads for K-tile kt have landed; keep later tiles in flight.
    if (kt < NT - 2)       asm volatile("s_waitcnt vmcnt(8)" ::: "memory");
    else if (kt == NT - 2) asm volatile("s_waitcnt vmcnt(4)" ::: "memory");
    else                   asm volatile("s_waitcnt vmcnt(0)" ::: "memory");
    __builtin_amdgcn_sched_barrier(0);
    // All waves confirmed their own tile-kt loads -> after this barrier the
    // whole tile is visible, and everyone is done reading tile kt-1's buffer.
    __builtin_amdgcn_s_barrier();
    asm volatile("" ::: "memory");

    if (kt + 3 < NT) STAGE(kt + 3);   // overwrites buffer of tile kt-1 (safe)

    const _Float16* As_ = lds + ((kt & 3) << 14);
    const _Float16* Bs_ = As_ + 8192;

    v8h a[8], b[4];
#pragma unroll
    for (int i = 0; i < 8; ++i)
      a[i] = *(const v8h*)&As_[(wm + i * 16 + fr) * 32 + fq * 8];
#pragma unroll
    for (int j = 0; j < 4; ++j)
      b[j] = *(const v8h*)&Bs_[(wn + j * 16 + fr) * 32 + fq * 8];

    __builtin_amdgcn_s_setprio(1);
#pragma unroll
    for (int i = 0; i < 8; ++i)
#pragma unroll
      for (int j = 0; j < 4; ++j)
        acc[i][j] = __builtin_amdgcn_mfma_f32_16x16x32_f16(a[i], b[j], acc[i][j], 0, 0, 0);
    __builtin_amdgcn_s_setprio(0);
    // Ensure no ds_read of this buffer is still outstanding when we pass the
    // next iteration's barrier (its STAGE overwrites this buffer).
    asm volatile("s_waitcnt lgkmcnt(0)" ::: "memory");
    __builtin_amdgcn_sched_barrier(0);
  }
#undef STAGE

  float* Cfb = Cf ? Cf + (long long)bz * sC : nullptr;
  _Float16* Chb = Ch ? Ch + (long long)bz * sC : nullptr;
#pragma unroll
  for (int i = 0; i < 8; ++i) {
#pragma unroll
    for (int j = 0; j < 4; ++j) {
#pragma unroll
      for (int r = 0; r < 4; ++r) {
        const int row = m0 + wm + i * 16 + fq * 4 + r;
        const int col = n0 + wn + j * 16 + fr;
        float v = acc[i][j][r];
        if (relu) v = fmaxf(v, 0.f);
        if (Cfb) Cfb[(long long)row * N + col] = v;
        if (Chb) Chb[(long long)row * N + col] = (_Float16)v;
      }
    }
  }
}

// ---------------------------------------------------------------------------
// Fused fp32->fp16 conversion of all four inputs in one launch.
// Each block handles 1024 elements of one of the arrays.
__global__ __launch_bounds__(256) void convert_all_kernel(
    const float* __restrict__ s0, _Float16* __restrict__ d0, int b0,  // k
    const float* __restrict__ s1, _Float16* __restrict__ d1, int b1,  // q
    const float* __restrict__ s2, _Float16* __restrict__ d2, int b2,  // Wk
    const float* __restrict__ s3, _Float16* __restrict__ d3)          // Wq
{
  int blk = blockIdx.x;
  const float* src;
  _Float16* dst;
  if (blk < b0)           { src = s0; dst = d0; }
  else if (blk < b0 + b1) { src = s1; dst = d1; blk -= b0; }
  else if (blk < b0 + b1 + b2) { src = s2; dst = d2; blk -= b0 + b1; }
  else                    { src = s3; dst = d3; blk -= b0 + b1 + b2; }
  const long long i = ((long long)blk * 256 + threadIdx.x) * 4;
  const float4 v = *(const float4*)(src + i);
  v4h o = {(_Float16)v.x, (_Float16)v.y, (_Float16)v.z, (_Float16)v.w};
  *(v4h*)(dst + i) = o;
}

// q [B,Q,H] fp32 -> qT [B,H,Q] fp16, 64x64 tiles
__global__ __launch_bounds__(256) void transpose_f16_kernel(
    const float* __restrict__ q, _Float16* __restrict__ qT, int Q, int H)
{
  __shared__ float tile[64][65];
  const float* qb = q + (long long)blockIdx.z * Q * H;
  _Float16* qTb = qT + (long long)blockIdx.z * H * Q;
  const int q0 = blockIdx.x * 64, h0 = blockIdx.y * 64;
  const int t = threadIdx.x;
  const int tr = t >> 4, tc = (t & 15) << 2;
#pragma unroll
  for (int i = 0; i < 4; ++i) {
    const float4 v = *(const float4*)(qb + (long long)(q0 + tr + i * 16) * H + h0 + tc);
    tile[tr + i * 16][tc + 0] = v.x;
    tile[tr + i * 16][tc + 1] = v.y;
    tile[tr + i * 16][tc + 2] = v.z;
    tile[tr + i * 16][tc + 3] = v.w;
  }
  __syncthreads();
#pragma unroll
  for (int i = 0; i < 4; ++i) {
    const int hl = tr + i * 16;
    const int ql = tc;
    v4h o = {(_Float16)tile[ql + 0][hl], (_Float16)tile[ql + 1][hl],
             (_Float16)tile[ql + 2][hl], (_Float16)tile[ql + 3][hl]};
    *(v4h*)(qTb + (long long)(h0 + hl) * Q + q0 + ql) = o;
  }
}

// softmax rows of S [B*P, Q] fp32 in place; also write fp16 copy
__global__ __launch_bounds__(256) void softmax_rows_kernel(
    float* __restrict__ S, _Float16* __restrict__ S16,
    const unsigned char* __restrict__ qmask, int Q, int P)
{
  const long long row = blockIdx.x;       // b*P + p
  const int b = (int)(row / P);
  float* s = S + row * (long long)Q;
  const unsigned char* msk = qmask + (long long)b * Q;
  const int t = threadIdx.x;
  float4 v = *(const float4*)(s + (t << 2));
  float vals[4] = {v.x, v.y, v.z, v.w};
#pragma unroll
  for (int j = 0; j < 4; ++j)
    if (msk[(t << 2) + j]) vals[j] = -INFINITY;

  __shared__ float red[8];
  const int wid = t >> 6, lid = t & 63;

  float mx = fmaxf(fmaxf(vals[0], vals[1]), fmaxf(vals[2], vals[3]));
#pragma unroll
  for (int o = 32; o > 0; o >>= 1) mx = fmaxf(mx, __shfl_xor(mx, o, 64));
  if (lid == 0) red[wid] = mx;
  __syncthreads();
  mx = fmaxf(fmaxf(red[0], red[1]), fmaxf(red[2], red[3]));

  float e[4];
  float sum = 0.f;
#pragma unroll
  for (int j = 0; j < 4; ++j) { e[j] = __expf(vals[j] - mx); sum += e[j]; }
#pragma unroll
  for (int o = 32; o > 0; o >>= 1) sum += __shfl_xor(sum, o, 64);
  __syncthreads();
  if (lid == 0) red[4 + wid] = sum;
  __syncthreads();
  sum = red[4] + red[5] + red[6] + red[7];
  const float inv = 1.f / sum;

  float4 o;
  o.x = e[0] * inv; o.y = e[1] * inv; o.z = e[2] * inv; o.w = e[3] * inv;
  *(float4*)(s + (t << 2)) = o;
  v4h oh = {(_Float16)o.x, (_Float16)o.y, (_Float16)o.z, (_Float16)o.w};
  *(v4h*)(S16 + row * (long long)Q + (t << 2)) = oh;
}

// ---------------------------------------------------------------------------
extern "C" void kernel_launch(void* const* d_in, const int* in_sizes, int n_in,
                              void* d_out, int out_size, void* d_ws, size_t ws_size,
                              hipStream_t stream)
{
  const int B = 8, P = 2048, Q = 1024, H = 1024;
  const float* k  = (const float*)d_in[0];
  const float* q  = (const float*)d_in[1];
  const unsigned char* qmask = (const unsigned char*)d_in[2];
  const float* Wk = (const float*)d_in[3];
  const float* Wq = (const float*)d_in[4];

  float* ctx    = (float*)d_out;                  // [B,P,H] fp32
  float* alphas = ctx + (size_t)B * P * H;        // [B,P,Q] fp32

  _Float16* pkey16 = (_Float16*)d_out;            // parked in ctx region

  char* wsb = (char*)d_ws;
  _Float16* qkey16   = (_Float16*)(wsb);                        // 16.78 MB
  _Float16* k16      = (_Float16*)(wsb + 16777216);             // 33.55 MB
  _Float16* alphas16 = k16;                                     // k16 dead after proj_k
  _Float16* q16      = (_Float16*)(wsb + 16777216 + 33554432);  // 16.78 MB
  _Float16* qT16     = q16;                                     // q16 dead after proj_q
  _Float16* Wk16     = (_Float16*)(wsb + 67108864);
  _Float16* Wq16     = (_Float16*)(wsb + 69206016);

  const long long nK = (long long)B * P * H;   // 16.78M
  const long long nQ = (long long)B * Q * H;   // 8.39M
  const long long nW = (long long)H * H;       // 1.05M

  // 1. fused converts
  const int bK = (int)(nK / 1024), bQ = (int)(nQ / 1024), bW = (int)(nW / 1024);
  convert_all_kernel<<<bK + bQ + 2 * bW, 256, 0, stream>>>(
      k, k16, bK, q, q16, bQ, Wk, Wk16, bW, Wq, Wq16);

  const size_t LDSB = 131072;   // 128 KB dynamic LDS
  // 2. pkey16 = relu(k16 @ Wk16^T)  [16384 x 1024], tiles 256x256
  gemm_nt_f16_256<<<64 * 4, 512, LDSB, stream>>>(
      k16, Wk16, nullptr, pkey16, H, H, 64, 4, 0LL, 0LL, 0LL, 1);
  // 3. qkey16 = relu(q16 @ Wq16^T)  [8192 x 1024]
  gemm_nt_f16_256<<<32 * 4, 512, LDSB, stream>>>(
      q16, Wq16, nullptr, qkey16, H, H, 32, 4, 0LL, 0LL, 0LL, 1);
  // 4. scores = pkey16 @ qkey16^T (batched) -> alphas slice fp32
  gemm_nt_f16_256<<<8 * 4 * B, 512, LDSB, stream>>>(
      pkey16, qkey16, alphas, nullptr, Q, H, 8, 4,
      (long long)P * H, (long long)Q * H, (long long)P * Q, 0);
  // 5. qT16 = q^T fp16 (overwrites q16)
  transpose_f16_kernel<<<dim3(Q / 64, H / 64, B), 256, 0, stream>>>(q, qT16, Q, H);
  // 6. softmax in place + fp16 copy (overwrites k16)
  softmax_rows_kernel<<<B * P, 256, 0, stream>>>(alphas, alphas16, qmask, Q, P);
  // 7. ctx = alphas16 @ qT16^T (batched NT) -> d_out base
  gemm_nt_f16_256<<<8 * 4 * B, 512, LDSB, stream>>>(
      alphas16, qT16, ctx, nullptr, H, Q, 8, 4,
      (long long)P * Q, (long long)H * Q, (long long)P * H, 0);
}

// Round 3
// 387.430 us; speedup vs baseline: 1.1391x; 1.0193x over previous
//
#include <hip/hip_runtime.h>
#include <hip/hip_bf16.h>
#include <math.h>

// B=8, P=2048, Q=1024, H=1024
// 1. convert k,q,Wk,Wq fp32 -> fp16 (single fused launch)
// 2. pkey16 = relu(k @ Wk^T)   MFMA f16 (parked in d_out ctx region)
// 3. qkey16 = relu(q @ Wq^T)   MFMA f16
// 4. scores = pkey @ qkey^T    MFMA f16, fp32 -> alphas slice of d_out
// 5. qT16 = transpose(q) fp16
// 6. softmax rows in place + fp16 alphas copy
// 7. ctx = alphas16 @ qT16^T   MFMA f16, fp32 -> d_out base
//
// GEMM: 256x256 tile, BK=64, 512 thr = 8 waves (2M x 4N), per-wave 128x64
// (acc[8][4] of 16x16x32 f16 frags). 2 LDS buffers x (A 32KB + B 32KB) =
// 128 KB. Schedule per K-tile t (m201-style, counted vmcnt):
//   issue STAGE(t+1) [8 x global_load_lds x16B]  (buffer t-1, freed by the
//      END barrier of iter t-1)
//   s_waitcnt vmcnt(8)   -> tile t's 8 loads landed; t+1's 8 stay in flight
//      across the barrier with a full iteration (~700cyc) of latency cover
//   s_barrier            -> tile t visible to all waves
//   4 phases: {ds_read subtile || 16 MFMA under setprio(1)}:
//      P0: read a[m0-3,kh01] + b[n0-1,kh01] -> MFMA (m0-3 x n0-1)
//      P1: read b[n2-3,kh01]                -> MFMA (m0-3 x n2-3)
//      P2: read a[m4-7,kh01]                -> MFMA (m4-7 x n2-3)
//      P3: (all regs live)                  -> MFMA (m4-7 x n0-1)
//   s_waitcnt lgkmcnt(0); s_barrier  -> buffer t-1.. (t+2's target) safe
// LDS XOR swizzle (BOTH sides, global_load_lds forces linear LDS dest):
//   row stride 128B == 0 mod banks, so unswizzled reads use only 4 of 8
//   16B-slots -> 2x serialization. Physical slot = logical ^ (row&7):
//   stage thread t fetches global col ((t&7)^((t>>3)&7))*8 (pre-swizzled
//   SOURCE, linear dest); reader at row R, slot s=kh*4+fq reads s^(R&7).
//   Gives uniform 8 accesses/bank (conflict-free).
// Tail: last iter has no STAGE -> vmcnt(0). NT = K/64 >= 2.

typedef _Float16 v8h __attribute__((ext_vector_type(8)));
typedef _Float16 v4h __attribute__((ext_vector_type(4)));
typedef float v4f __attribute__((ext_vector_type(4)));

#define AS1C(p) ((const __attribute__((address_space(1))) void*)(p))
#define AS3(p)  ((__attribute__((address_space(3))) void*)(p))

// ---------------------------------------------------------------------------
// NT MFMA GEMM: C[m,n] = sum_k A[m,k]*B[n,k], A:[M,K] B:[N,K] row-major f16.
// Grid multiple of 8 (XCD swizzle); M%256==0, N%256==0, K%64==0, K>=128.
__global__ __launch_bounds__(512) void gemm_nt_f16_256(
    const _Float16* __restrict__ A, const _Float16* __restrict__ B,
    float* __restrict__ Cf, _Float16* __restrict__ Ch,
    int N, int K, int Mtiles, int Ntiles,
    long long sA, long long sB, long long sC, int relu)
{
  extern __shared__ _Float16 lds[];   // 2 bufs x (A 16384 elems | B 16384 elems)

  // XCD-aware swizzle (nwg % 8 == 0 for all our grids), M-fastest decode.
  const int nwg = gridDim.x;
  const int cpx = nwg >> 3;
  const int bid = (blockIdx.x & 7) * cpx + (blockIdx.x >> 3);
  const int mt  = bid % Mtiles;
  const int nt  = (bid / Mtiles) % Ntiles;
  const int bz  = bid / (Mtiles * Ntiles);

  A += (long long)bz * sA;
  B += (long long)bz * sB;

  const int m0 = mt * 256;
  const int n0 = nt * 256;
  const int t  = threadIdx.x;       // 0..511
  const int l  = t & 63;
  const int w  = t >> 6;            // 0..7
  const int wm = (w >> 2) * 128;    // wave m offset: 0 or 128
  const int wn = (w & 3) * 64;      // wave n offset: 0,64,128,192
  const int fr = l & 15;
  const int fq = l >> 4;
  const int r3 = fr & 7;
  // swizzled 16B-slot (in fp16 elems, *8) for kh=0 and kh=1 fragment reads
  const int sa0 = (fq ^ r3) * 8;
  const int sa1 = ((4 + fq) ^ r3) * 8;

  // Staging: thread t covers LDS bytes [t*16, t*16+16) of each 8KB chunk
  // (64 rows x 128B). Linear LDS row = chunk*64 + (t>>3), phys slot = t&7.
  // Pre-swizzled global col: logical slot = (t&7) ^ ((t>>3)&7).
  const int trow = t >> 3;                       // 0..63
  const int tswz = ((t & 7) ^ (trow & 7)) * 8;   // fp16 elems

  const _Float16* Ast = A + (long long)(m0 + trow) * K + tswz;
  const _Float16* Bst = B + (long long)(n0 + trow) * K + tswz;

  v4f acc[8][4];
#pragma unroll
  for (int i = 0; i < 8; ++i)
#pragma unroll
    for (int j = 0; j < 4; ++j)
      acc[i][j] = (v4f){0.f, 0.f, 0.f, 0.f};

  const int NT = K >> 6;            // K-tiles of 64

#define STAGE(kt) do {                                                                   \
    _Float16* s_ = lds + (((kt) & 1) << 15);                                             \
    const long long ko_ = (long long)((kt) << 6);                                        \
    __builtin_amdgcn_global_load_lds(AS1C(Ast + ko_),                AS3(s_ +         t * 8), 16, 0, 0); \
    __builtin_amdgcn_global_load_lds(AS1C(Ast +  64LL * K + ko_),    AS3(s_ +  4096 + t * 8), 16, 0, 0); \
    __builtin_amdgcn_global_load_lds(AS1C(Ast + 128LL * K + ko_),    AS3(s_ +  8192 + t * 8), 16, 0, 0); \
    __builtin_amdgcn_global_load_lds(AS1C(Ast + 192LL * K + ko_),    AS3(s_ + 12288 + t * 8), 16, 0, 0); \
    __builtin_amdgcn_global_load_lds(AS1C(Bst + ko_),                AS3(s_ + 16384 + t * 8), 16, 0, 0); \
    __builtin_amdgcn_global_load_lds(AS1C(Bst +  64LL * K + ko_),    AS3(s_ + 20480 + t * 8), 16, 0, 0); \
    __builtin_amdgcn_global_load_lds(AS1C(Bst + 128LL * K + ko_),    AS3(s_ + 24576 + t * 8), 16, 0, 0); \
    __builtin_amdgcn_global_load_lds(AS1C(Bst + 192LL * K + ko_),    AS3(s_ + 28672 + t * 8), 16, 0, 0); \
  } while (0)

  STAGE(0);   // prologue: tile 0 in flight (8 loads)

  for (int kt = 0; kt < NT; ++kt) {
    if (kt + 1 < NT) {
      STAGE(kt + 1);   // buffer (kt+1)&1, freed by END barrier of iter kt-1
      asm volatile("s_waitcnt vmcnt(8)" ::: "memory");   // tile kt landed
    } else {
      asm volatile("s_waitcnt vmcnt(0)" ::: "memory");
    }
    __builtin_amdgcn_sched_barrier(0);
    __builtin_amdgcn_s_barrier();        // tile kt visible to all waves
    asm volatile("" ::: "memory");

    const _Float16* Ab = lds + ((kt & 1) << 15);
    const _Float16* Bb = Ab + 16384;

    v8h a0[4], a1[4], b0[4], b1[4];

    // P0: a rows m0-3 (both kh) + b cols n0-1 (both kh) -> quadrant (m0-3 x n0-1)
#pragma unroll
    for (int i = 0; i < 4; ++i) {
      a0[i] = *(const v8h*)&Ab[(wm + i * 16 + fr) * 64 + sa0];
      a1[i] = *(const v8h*)&Ab[(wm + i * 16 + fr) * 64 + sa1];
    }
#pragma unroll
    for (int j = 0; j < 2; ++j) {
      b0[j] = *(const v8h*)&Bb[(wn + j * 16 + fr) * 64 + sa0];
      b1[j] = *(const v8h*)&Bb[(wn + j * 16 + fr) * 64 + sa1];
    }
    __builtin_amdgcn_s_setprio(1);
#pragma unroll
    for (int i = 0; i < 4; ++i)
#pragma unroll
      for (int j = 0; j < 2; ++j) {
        acc[i][j] = __builtin_amdgcn_mfma_f32_16x16x32_f16(a0[i], b0[j], acc[i][j], 0, 0, 0);
        acc[i][j] = __builtin_amdgcn_mfma_f32_16x16x32_f16(a1[i], b1[j], acc[i][j], 0, 0, 0);
      }
    __builtin_amdgcn_s_setprio(0);

    // P1: b cols n2-3 -> quadrant (m0-3 x n2-3)
#pragma unroll
    for (int j = 2; j < 4; ++j) {
      b0[j] = *(const v8h*)&Bb[(wn + j * 16 + fr) * 64 + sa0];
      b1[j] = *(const v8h*)&Bb[(wn + j * 16 + fr) * 64 + sa1];
    }
    __builtin_amdgcn_s_setprio(1);
#pragma unroll
    for (int i = 0; i < 4; ++i)
#pragma unroll
      for (int j = 2; j < 4; ++j) {
        acc[i][j] = __builtin_amdgcn_mfma_f32_16x16x32_f16(a0[i], b0[j], acc[i][j], 0, 0, 0);
        acc[i][j] = __builtin_amdgcn_mfma_f32_16x16x32_f16(a1[i], b1[j], acc[i][j], 0, 0, 0);
      }
    __builtin_amdgcn_s_setprio(0);

    // P2: a rows m4-7 (overwrite a regs) -> quadrant (m4-7 x n2-3)
#pragma unroll
    for (int i = 0; i < 4; ++i) {
      a0[i] = *(const v8h*)&Ab[(wm + 64 + i * 16 + fr) * 64 + sa0];
      a1[i] = *(const v8h*)&Ab[(wm + 64 + i * 16 + fr) * 64 + sa1];
    }
    __builtin_amdgcn_s_setprio(1);
#pragma unroll
    for (int i = 0; i < 4; ++i)
#pragma unroll
      for (int j = 2; j < 4; ++j) {
        acc[4 + i][j] = __builtin_amdgcn_mfma_f32_16x16x32_f16(a0[i], b0[j], acc[4 + i][j], 0, 0, 0);
        acc[4 + i][j] = __builtin_amdgcn_mfma_f32_16x16x32_f16(a1[i], b1[j], acc[4 + i][j], 0, 0, 0);
      }
    __builtin_amdgcn_s_setprio(0);

    // P3: all regs live -> quadrant (m4-7 x n0-1)
    __builtin_amdgcn_s_setprio(1);
#pragma unroll
    for (int i = 0; i < 4; ++i)
#pragma unroll
      for (int j = 0; j < 2; ++j) {
        acc[4 + i][j] = __builtin_amdgcn_mfma_f32_16x16x32_f16(a0[i], b0[j], acc[4 + i][j], 0, 0, 0);
        acc[4 + i][j] = __builtin_amdgcn_mfma_f32_16x16x32_f16(a1[i], b1[j], acc[4 + i][j], 0, 0, 0);
      }
    __builtin_amdgcn_s_setprio(0);

    // All own ds_reads of buffer kt done before signaling; after this barrier
    // every wave has finished reading buffer kt -> STAGE(kt+2) may overwrite.
    asm volatile("s_waitcnt lgkmcnt(0)" ::: "memory");
    __builtin_amdgcn_sched_barrier(0);
    __builtin_amdgcn_s_barrier();
  }
#undef STAGE

  float* Cfb = Cf ? Cf + (long long)bz * sC : nullptr;
  _Float16* Chb = Ch ? Ch + (long long)bz * sC : nullptr;
#pragma unroll
  for (int mh = 0; mh < 2; ++mh) {
#pragma unroll
    for (int i = 0; i < 4; ++i) {
#pragma unroll
      for (int j = 0; j < 4; ++j) {
#pragma unroll
        for (int r = 0; r < 4; ++r) {
          const int row = m0 + wm + mh * 64 + i * 16 + fq * 4 + r;
          const int col = n0 + wn + j * 16 + fr;
          float v = acc[mh * 4 + i][j][r];
          if (relu) v = fmaxf(v, 0.f);
          if (Cfb) Cfb[(long long)row * N + col] = v;
          if (Chb) Chb[(long long)row * N + col] = (_Float16)v;
        }
      }
    }
  }
}

// ---------------------------------------------------------------------------
// Fused fp32->fp16 conversion of all four inputs in one launch.
// Each block handles 1024 elements of one of the arrays.
__global__ __launch_bounds__(256) void convert_all_kernel(
    const float* __restrict__ s0, _Float16* __restrict__ d0, int b0,  // k
    const float* __restrict__ s1, _Float16* __restrict__ d1, int b1,  // q
    const float* __restrict__ s2, _Float16* __restrict__ d2, int b2,  // Wk
    const float* __restrict__ s3, _Float16* __restrict__ d3)          // Wq
{
  int blk = blockIdx.x;
  const float* src;
  _Float16* dst;
  if (blk < b0)           { src = s0; dst = d0; }
  else if (blk < b0 + b1) { src = s1; dst = d1; blk -= b0; }
  else if (blk < b0 + b1 + b2) { src = s2; dst = d2; blk -= b0 + b1; }
  else                    { src = s3; dst = d3; blk -= b0 + b1 + b2; }
  const long long i = ((long long)blk * 256 + threadIdx.x) * 4;
  const float4 v = *(const float4*)(src + i);
  v4h o = {(_Float16)v.x, (_Float16)v.y, (_Float16)v.z, (_Float16)v.w};
  *(v4h*)(dst + i) = o;
}

// q [B,Q,H] fp32 -> qT [B,H,Q] fp16, 64x64 tiles
__global__ __launch_bounds__(256) void transpose_f16_kernel(
    const float* __restrict__ q, _Float16* __restrict__ qT, int Q, int H)
{
  __shared__ float tile[64][65];
  const float* qb = q + (long long)blockIdx.z * Q * H;
  _Float16* qTb = qT + (long long)blockIdx.z * H * Q;
  const int q0 = blockIdx.x * 64, h0 = blockIdx.y * 64;
  const int t = threadIdx.x;
  const int tr = t >> 4, tc = (t & 15) << 2;
#pragma unroll
  for (int i = 0; i < 4; ++i) {
    const float4 v = *(const float4*)(qb + (long long)(q0 + tr + i * 16) * H + h0 + tc);
    tile[tr + i * 16][tc + 0] = v.x;
    tile[tr + i * 16][tc + 1] = v.y;
    tile[tr + i * 16][tc + 2] = v.z;
    tile[tr + i * 16][tc + 3] = v.w;
  }
  __syncthreads();
#pragma unroll
  for (int i = 0; i < 4; ++i) {
    const int hl = tr + i * 16;
    const int ql = tc;
    v4h o = {(_Float16)tile[ql + 0][hl], (_Float16)tile[ql + 1][hl],
             (_Float16)tile[ql + 2][hl], (_Float16)tile[ql + 3][hl]};
    *(v4h*)(qTb + (long long)(h0 + hl) * Q + q0 + ql) = o;
  }
}

// softmax rows of S [B*P, Q] fp32 in place; also write fp16 copy
__global__ __launch_bounds__(256) void softmax_rows_kernel(
    float* __restrict__ S, _Float16* __restrict__ S16,
    const unsigned char* __restrict__ qmask, int Q, int P)
{
  const long long row = blockIdx.x;       // b*P + p
  const int b = (int)(row / P);
  float* s = S + row * (long long)Q;
  const unsigned char* msk = qmask + (long long)b * Q;
  const int t = threadIdx.x;
  float4 v = *(const float4*)(s + (t << 2));
  float vals[4] = {v.x, v.y, v.z, v.w};
#pragma unroll
  for (int j = 0; j < 4; ++j)
    if (msk[(t << 2) + j]) vals[j] = -INFINITY;

  __shared__ float red[8];
  const int wid = t >> 6, lid = t & 63;

  float mx = fmaxf(fmaxf(vals[0], vals[1]), fmaxf(vals[2], vals[3]));
#pragma unroll
  for (int o = 32; o > 0; o >>= 1) mx = fmaxf(mx, __shfl_xor(mx, o, 64));
  if (lid == 0) red[wid] = mx;
  __syncthreads();
  mx = fmaxf(fmaxf(red[0], red[1]), fmaxf(red[2], red[3]));

  float e[4];
  float sum = 0.f;
#pragma unroll
  for (int j = 0; j < 4; ++j) { e[j] = __expf(vals[j] - mx); sum += e[j]; }
#pragma unroll
  for (int o = 32; o > 0; o >>= 1) sum += __shfl_xor(sum, o, 64);
  __syncthreads();
  if (lid == 0) red[4 + wid] = sum;
  __syncthreads();
  sum = red[4] + red[5] + red[6] + red[7];
  const float inv = 1.f / sum;

  float4 o;
  o.x = e[0] * inv; o.y = e[1] * inv; o.z = e[2] * inv; o.w = e[3] * inv;
  *(float4*)(s + (t << 2)) = o;
  v4h oh = {(_Float16)o.x, (_Float16)o.y, (_Float16)o.z, (_Float16)o.w};
  *(v4h*)(S16 + row * (long long)Q + (t << 2)) = oh;
}

// ---------------------------------------------------------------------------
extern "C" void kernel_launch(void* const* d_in, const int* in_sizes, int n_in,
                              void* d_out, int out_size, void* d_ws, size_t ws_size,
                              hipStream_t stream)
{
  const int B = 8, P = 2048, Q = 1024, H = 1024;
  const float* k  = (const float*)d_in[0];
  const float* q  = (const float*)d_in[1];
  const unsigned char* qmask = (const unsigned char*)d_in[2];
  const float* Wk = (const float*)d_in[3];
  const float* Wq = (const float*)d_in[4];

  float* ctx    = (float*)d_out;                  // [B,P,H] fp32
  float* alphas = ctx + (size_t)B * P * H;        // [B,P,Q] fp32

  _Float16* pkey16 = (_Float16*)d_out;            // parked in ctx region

  char* wsb = (char*)d_ws;
  _Float16* qkey16   = (_Float16*)(wsb);                        // 16.78 MB
  _Float16* k16      = (_Float16*)(wsb + 16777216);             // 33.55 MB
  _Float16* alphas16 = k16;                                     // k16 dead after proj_k
  _Float16* q16      = (_Float16*)(wsb + 16777216 + 33554432);  // 16.78 MB
  _Float16* qT16     = q16;                                     // q16 dead after proj_q
  _Float16* Wk16     = (_Float16*)(wsb + 67108864);
  _Float16* Wq16     = (_Float16*)(wsb + 69206016);

  const long long nK = (long long)B * P * H;   // 16.78M
  const long long nQ = (long long)B * Q * H;   // 8.39M
  const long long nW = (long long)H * H;       // 1.05M

  // 1. fused converts
  const int bK = (int)(nK / 1024), bQ = (int)(nQ / 1024), bW = (int)(nW / 1024);
  convert_all_kernel<<<bK + bQ + 2 * bW, 256, 0, stream>>>(
      k, k16, bK, q, q16, bQ, Wk, Wk16, bW, Wq, Wq16);

  const size_t LDSB = 131072;   // 128 KB dynamic LDS
  // 2. pkey16 = relu(k16 @ Wk16^T)  [16384 x 1024], tiles 256x256
  gemm_nt_f16_256<<<64 * 4, 512, LDSB, stream>>>(
      k16, Wk16, nullptr, pkey16, H, H, 64, 4, 0LL, 0LL, 0LL, 1);
  // 3. qkey16 = relu(q16 @ Wq16^T)  [8192 x 1024]
  gemm_nt_f16_256<<<32 * 4, 512, LDSB, stream>>>(
      q16, Wq16, nullptr, qkey16, H, H, 32, 4, 0LL, 0LL, 0LL, 1);
  // 4. scores = pkey16 @ qkey16^T (batched) -> alphas slice fp32
  gemm_nt_f16_256<<<8 * 4 * B, 512, LDSB, stream>>>(
      pkey16, qkey16, alphas, nullptr, Q, H, 8, 4,
      (long long)P * H, (long long)Q * H, (long long)P * Q, 0);
  // 5. qT16 = q^T fp16 (overwrites q16)
  transpose_f16_kernel<<<dim3(Q / 64, H / 64, B), 256, 0, stream>>>(q, qT16, Q, H);
  // 6. softmax in place + fp16 copy (overwrites k16)
  softmax_rows_kernel<<<B * P, 256, 0, stream>>>(alphas, alphas16, qmask, Q, P);
  // 7. ctx = alphas16 @ qT16^T (batched NT) -> d_out base
  gemm_nt_f16_256<<<8 * 4 * B, 512, LDSB, stream>>>(
      alphas16, qT16, ctx, nullptr, H, Q, 8, 4,
      (long long)P * Q, (long long)H * Q, (long long)P * H, 0);
}

// Round 4
// 380.077 us; speedup vs baseline: 1.1611x; 1.0193x over previous
//
#include <hip/hip_runtime.h>
#include <hip/hip_bf16.h>
#include <math.h>

// B=8, P=2048, Q=1024, H=1024
// 1. convert k,q,Wk,Wq fp32 -> fp16 (single fused launch)
// 2. fused proj: pkey16 = relu(k @ Wk^T), qkey16 = relu(q @ Wq^T) in ONE
//    launch (k16/q16 contiguous in ws -> one [24576,1024] A; mt-split picks
//    weight + dest). pkey16 parked in d_out ctx region.
// 3. scores = pkey @ qkey^T    MFMA f16, fp32 -> alphas slice of d_out
// 4. qT16 = transpose(q) fp16
// 5. softmax rows in place + fp16 alphas copy
// 6. ctx = alphas16 @ qT16^T   MFMA f16, fp32 -> d_out base
//
// GEMM: 128x128 tile, BK=64, 256 thr = 4 waves (2x2), per-wave 64x64
// (acc[4][4]). 2 LDS buffers x 32KB = 64KB -> 2 BLOCKS/CU (the R3 256-tile
// at 128KB was 1 block/CU: its epilogue (256KB fp32 ~26k cyc at HBM rate),
// prologue, and vmcnt stalls were all SERIAL per CU. With 2 co-resident
// blocks these overlap the neighbor's K-loop; grids are 1024 blocks = 4
// resident passes, amortizing tails.)
// Schedule per K-tile t (unchanged from R3, verified correct):
//   STAGE(t+1) [8 x global_load_lds x16B] -> s_waitcnt vmcnt(8) (tile t
//   landed, t+1 stays in flight across the barrier) -> s_barrier ->
//   2 phases {ds_read subtile -> 16 MFMA under setprio(1)} ->
//   lgkmcnt(0) -> s_barrier (frees buffer for t+2's STAGE).
// LDS XOR swizzle (both sides; global_load_lds forces linear LDS dest):
//   BK=64 rows are 128B (= 0 mod banks). Physical 16B-slot = logical ^
//   (row&7): stage thread fetches pre-swizzled global col, reader XORs.
//   Uniform 8 accesses/bank (verified: absmax unchanged R2->R3).

typedef _Float16 v8h __attribute__((ext_vector_type(8)));
typedef _Float16 v4h __attribute__((ext_vector_type(4)));
typedef float v4f __attribute__((ext_vector_type(4)));

#define AS1C(p) ((const __attribute__((address_space(1))) void*)(p))
#define AS3(p)  ((__attribute__((address_space(3))) void*)(p))

// ---------------------------------------------------------------------------
// NT MFMA GEMM: C[m,n] = sum_k A[m,k]*B[n,k], A:[M,K] B:[N,K] row-major f16.
// Grid multiple of 8 (XCD swizzle); tiles 128x128, K%64==0, K>=128.
// mt >= mtSplit switches to {B2, Ch2} with re-based output row (A stays
// contiguous) -- used to fuse the two relu-projections.
__global__ __launch_bounds__(256) void gemm_nt_f16_128(
    const _Float16* __restrict__ A, const _Float16* __restrict__ B,
    float* __restrict__ Cf, _Float16* __restrict__ Ch,
    const _Float16* __restrict__ B2, _Float16* __restrict__ Ch2, int mtSplit,
    int N, int K, int Mtiles, int Ntiles,
    long long sA, long long sB, long long sC, int relu)
{
  extern __shared__ _Float16 lds[];   // 2 bufs x (A 8192 elems | B 8192 elems)

  // XCD-aware swizzle (nwg % 8 == 0 for all our grids), M-fastest decode.
  const int nwg = gridDim.x;
  const int cpx = nwg >> 3;
  const int bid = (blockIdx.x & 7) * cpx + (blockIdx.x >> 3);
  const int mt  = bid % Mtiles;
  const int nt  = (bid / Mtiles) % Ntiles;
  const int bz  = bid / (Mtiles * Ntiles);

  A += (long long)bz * sA;

  const _Float16* Bp = B;
  _Float16* Chp = Ch;
  int m0c = mt * 128;                 // output row base
  if (mt >= mtSplit) { Bp = B2; Chp = Ch2; m0c = (mt - mtSplit) * 128; }
  Bp += (long long)bz * sB;

  const int m0g = mt * 128;           // A row base (contiguous across split)
  const int n0  = nt * 128;
  const int t   = threadIdx.x;        // 0..255
  const int l   = t & 63;
  const int w   = t >> 6;             // 0..3
  const int wm  = (w >> 1) * 64;      // wave m offset: 0 or 64
  const int wn  = (w & 1) * 64;       // wave n offset: 0 or 64
  const int fr  = l & 15;
  const int fq  = l >> 4;
  const int r3  = fr & 7;
  // swizzled 16B-slot (in fp16 elems, *8) for kh=0 and kh=1 fragment reads
  const int sa0 = (fq ^ r3) * 8;
  const int sa1 = ((4 + fq) ^ r3) * 8;

  // Staging: 8 insts x 256 thr x 16B = 64KB... per buffer 32KB (A 16KB + B
  // 16KB). Each inst covers 32 rows x 128B. Thread t: row-in-chunk = t>>3,
  // phys slot = t&7, pre-swizzled global col = ((t&7)^(row&7))*8.
  const int trow = t >> 3;                       // 0..31
  const int tswz = ((t & 7) ^ (trow & 7)) * 8;   // fp16 elems

  const _Float16* Ast = A  + (long long)(m0g + trow) * K + tswz;
  const _Float16* Bst = Bp + (long long)(n0  + trow) * K + tswz;

  v4f acc[4][4];
#pragma unroll
  for (int i = 0; i < 4; ++i)
#pragma unroll
    for (int j = 0; j < 4; ++j)
      acc[i][j] = (v4f){0.f, 0.f, 0.f, 0.f};

  const int NT = K >> 6;            // K-tiles of 64

#define STAGE(kt) do {                                                                   \
    _Float16* s_ = lds + (((kt) & 1) << 14);                                             \
    const long long ko_ = (long long)((kt) << 6);                                        \
    __builtin_amdgcn_global_load_lds(AS1C(Ast + ko_),               AS3(s_ +        t * 8), 16, 0, 0); \
    __builtin_amdgcn_global_load_lds(AS1C(Ast + 32LL * K + ko_),    AS3(s_ + 2048 + t * 8), 16, 0, 0); \
    __builtin_amdgcn_global_load_lds(AS1C(Ast + 64LL * K + ko_),    AS3(s_ + 4096 + t * 8), 16, 0, 0); \
    __builtin_amdgcn_global_load_lds(AS1C(Ast + 96LL * K + ko_),    AS3(s_ + 6144 + t * 8), 16, 0, 0); \
    __builtin_amdgcn_global_load_lds(AS1C(Bst + ko_),               AS3(s_ + 8192 + t * 8), 16, 0, 0); \
    __builtin_amdgcn_global_load_lds(AS1C(Bst + 32LL * K + ko_),    AS3(s_ + 10240 + t * 8), 16, 0, 0); \
    __builtin_amdgcn_global_load_lds(AS1C(Bst + 64LL * K + ko_),    AS3(s_ + 12288 + t * 8), 16, 0, 0); \
    __builtin_amdgcn_global_load_lds(AS1C(Bst + 96LL * K + ko_),    AS3(s_ + 14336 + t * 8), 16, 0, 0); \
  } while (0)

  STAGE(0);   // prologue: tile 0 in flight (8 loads)

  for (int kt = 0; kt < NT; ++kt) {
    if (kt + 1 < NT) {
      STAGE(kt + 1);   // buffer (kt+1)&1, freed by END barrier of iter kt-1
      asm volatile("s_waitcnt vmcnt(8)" ::: "memory");   // tile kt landed
    } else {
      asm volatile("s_waitcnt vmcnt(0)" ::: "memory");
    }
    __builtin_amdgcn_sched_barrier(0);
    __builtin_amdgcn_s_barrier();        // tile kt visible to all waves
    asm volatile("" ::: "memory");

    const _Float16* Ab = lds + ((kt & 1) << 14);
    const _Float16* Bb = Ab + 8192;

    v8h a0[4], a1[4], b0[4], b1[4];

    // P0: a rows i0-3 (both kh) + b cols j0-1 (both kh) -> 16 MFMA
#pragma unroll
    for (int i = 0; i < 4; ++i) {
      a0[i] = *(const v8h*)&Ab[(wm + i * 16 + fr) * 64 + sa0];
      a1[i] = *(const v8h*)&Ab[(wm + i * 16 + fr) * 64 + sa1];
    }
#pragma unroll
    for (int j = 0; j < 2; ++j) {
      b0[j] = *(const v8h*)&Bb[(wn + j * 16 + fr) * 64 + sa0];
      b1[j] = *(const v8h*)&Bb[(wn + j * 16 + fr) * 64 + sa1];
    }
    __builtin_amdgcn_s_setprio(1);
#pragma unroll
    for (int i = 0; i < 4; ++i)
#pragma unroll
      for (int j = 0; j < 2; ++j) {
        acc[i][j] = __builtin_amdgcn_mfma_f32_16x16x32_f16(a0[i], b0[j], acc[i][j], 0, 0, 0);
        acc[i][j] = __builtin_amdgcn_mfma_f32_16x16x32_f16(a1[i], b1[j], acc[i][j], 0, 0, 0);
      }
    __builtin_amdgcn_s_setprio(0);

    // P1: b cols j2-3 -> 16 MFMA
#pragma unroll
    for (int j = 2; j < 4; ++j) {
      b0[j] = *(const v8h*)&Bb[(wn + j * 16 + fr) * 64 + sa0];
      b1[j] = *(const v8h*)&Bb[(wn + j * 16 + fr) * 64 + sa1];
    }
    __builtin_amdgcn_s_setprio(1);
#pragma unroll
    for (int i = 0; i < 4; ++i)
#pragma unroll
      for (int j = 2; j < 4; ++j) {
        acc[i][j] = __builtin_amdgcn_mfma_f32_16x16x32_f16(a0[i], b0[j], acc[i][j], 0, 0, 0);
        acc[i][j] = __builtin_amdgcn_mfma_f32_16x16x32_f16(a1[i], b1[j], acc[i][j], 0, 0, 0);
      }
    __builtin_amdgcn_s_setprio(0);

    // All own ds_reads of buffer kt done before signaling; after this barrier
    // every wave finished reading buffer kt -> STAGE(kt+2) may overwrite.
    asm volatile("s_waitcnt lgkmcnt(0)" ::: "memory");
    __builtin_amdgcn_sched_barrier(0);
    __builtin_amdgcn_s_barrier();
  }
#undef STAGE

  float* Cfb = Cf ? Cf + (long long)bz * sC : nullptr;
  _Float16* Chb = Chp ? Chp + (long long)bz * sC : nullptr;
#pragma unroll
  for (int i = 0; i < 4; ++i) {
#pragma unroll
    for (int j = 0; j < 4; ++j) {
#pragma unroll
      for (int r = 0; r < 4; ++r) {
        const int row = m0c + wm + i * 16 + fq * 4 + r;
        const int col = n0 + wn + j * 16 + fr;
        float v = acc[i][j][r];
        if (relu) v = fmaxf(v, 0.f);
        if (Cfb) Cfb[(long long)row * N + col] = v;
        if (Chb) Chb[(long long)row * N + col] = (_Float16)v;
      }
    }
  }
}

// ---------------------------------------------------------------------------
// Fused fp32->fp16 conversion of all four inputs in one launch.
// Each block handles 1024 elements of one of the arrays.
__global__ __launch_bounds__(256) void convert_all_kernel(
    const float* __restrict__ s0, _Float16* __restrict__ d0, int b0,  // k
    const float* __restrict__ s1, _Float16* __restrict__ d1, int b1,  // q
    const float* __restrict__ s2, _Float16* __restrict__ d2, int b2,  // Wk
    const float* __restrict__ s3, _Float16* __restrict__ d3)          // Wq
{
  int blk = blockIdx.x;
  const float* src;
  _Float16* dst;
  if (blk < b0)           { src = s0; dst = d0; }
  else if (blk < b0 + b1) { src = s1; dst = d1; blk -= b0; }
  else if (blk < b0 + b1 + b2) { src = s2; dst = d2; blk -= b0 + b1; }
  else                    { src = s3; dst = d3; blk -= b0 + b1 + b2; }
  const long long i = ((long long)blk * 256 + threadIdx.x) * 4;
  const float4 v = *(const float4*)(src + i);
  v4h o = {(_Float16)v.x, (_Float16)v.y, (_Float16)v.z, (_Float16)v.w};
  *(v4h*)(dst + i) = o;
}

// q [B,Q,H] fp32 -> qT [B,H,Q] fp16, 64x64 tiles
__global__ __launch_bounds__(256) void transpose_f16_kernel(
    const float* __restrict__ q, _Float16* __restrict__ qT, int Q, int H)
{
  __shared__ float tile[64][65];
  const float* qb = q + (long long)blockIdx.z * Q * H;
  _Float16* qTb = qT + (long long)blockIdx.z * H * Q;
  const int q0 = blockIdx.x * 64, h0 = blockIdx.y * 64;
  const int t = threadIdx.x;
  const int tr = t >> 4, tc = (t & 15) << 2;
#pragma unroll
  for (int i = 0; i < 4; ++i) {
    const float4 v = *(const float4*)(qb + (long long)(q0 + tr + i * 16) * H + h0 + tc);
    tile[tr + i * 16][tc + 0] = v.x;
    tile[tr + i * 16][tc + 1] = v.y;
    tile[tr + i * 16][tc + 2] = v.z;
    tile[tr + i * 16][tc + 3] = v.w;
  }
  __syncthreads();
#pragma unroll
  for (int i = 0; i < 4; ++i) {
    const int hl = tr + i * 16;
    const int ql = tc;
    v4h o = {(_Float16)tile[ql + 0][hl], (_Float16)tile[ql + 1][hl],
             (_Float16)tile[ql + 2][hl], (_Float16)tile[ql + 3][hl]};
    *(v4h*)(qTb + (long long)(h0 + hl) * Q + q0 + ql) = o;
  }
}

// softmax rows of S [B*P, Q] fp32 in place; also write fp16 copy
__global__ __launch_bounds__(256) void softmax_rows_kernel(
    float* __restrict__ S, _Float16* __restrict__ S16,
    const unsigned char* __restrict__ qmask, int Q, int P)
{
  const long long row = blockIdx.x;       // b*P + p
  const int b = (int)(row / P);
  float* s = S + row * (long long)Q;
  const unsigned char* msk = qmask + (long long)b * Q;
  const int t = threadIdx.x;
  float4 v = *(const float4*)(s + (t << 2));
  float vals[4] = {v.x, v.y, v.z, v.w};
#pragma unroll
  for (int j = 0; j < 4; ++j)
    if (msk[(t << 2) + j]) vals[j] = -INFINITY;

  __shared__ float red[8];
  const int wid = t >> 6, lid = t & 63;

  float mx = fmaxf(fmaxf(vals[0], vals[1]), fmaxf(vals[2], vals[3]));
#pragma unroll
  for (int o = 32; o > 0; o >>= 1) mx = fmaxf(mx, __shfl_xor(mx, o, 64));
  if (lid == 0) red[wid] = mx;
  __syncthreads();
  mx = fmaxf(fmaxf(red[0], red[1]), fmaxf(red[2], red[3]));

  float e[4];
  float sum = 0.f;
#pragma unroll
  for (int j = 0; j < 4; ++j) { e[j] = __expf(vals[j] - mx); sum += e[j]; }
#pragma unroll
  for (int o = 32; o > 0; o >>= 1) sum += __shfl_xor(sum, o, 64);
  __syncthreads();
  if (lid == 0) red[4 + wid] = sum;
  __syncthreads();
  sum = red[4] + red[5] + red[6] + red[7];
  const float inv = 1.f / sum;

  float4 o;
  o.x = e[0] * inv; o.y = e[1] * inv; o.z = e[2] * inv; o.w = e[3] * inv;
  *(float4*)(s + (t << 2)) = o;
  v4h oh = {(_Float16)o.x, (_Float16)o.y, (_Float16)o.z, (_Float16)o.w};
  *(v4h*)(S16 + row * (long long)Q + (t << 2)) = oh;
}

// ---------------------------------------------------------------------------
extern "C" void kernel_launch(void* const* d_in, const int* in_sizes, int n_in,
                              void* d_out, int out_size, void* d_ws, size_t ws_size,
                              hipStream_t stream)
{
  const int B = 8, P = 2048, Q = 1024, H = 1024;
  const float* k  = (const float*)d_in[0];
  const float* q  = (const float*)d_in[1];
  const unsigned char* qmask = (const unsigned char*)d_in[2];
  const float* Wk = (const float*)d_in[3];
  const float* Wq = (const float*)d_in[4];

  float* ctx    = (float*)d_out;                  // [B,P,H] fp32
  float* alphas = ctx + (size_t)B * P * H;        // [B,P,Q] fp32

  _Float16* pkey16 = (_Float16*)d_out;            // parked in ctx region

  char* wsb = (char*)d_ws;
  _Float16* qkey16   = (_Float16*)(wsb);                        // 16.78 MB
  _Float16* k16      = (_Float16*)(wsb + 16777216);             // 33.55 MB
  _Float16* alphas16 = k16;                                     // k16 dead after proj
  _Float16* q16      = (_Float16*)(wsb + 16777216 + 33554432);  // 16.78 MB, CONTIGUOUS after k16
  _Float16* qT16     = q16;                                     // q16 dead after proj
  _Float16* Wk16     = (_Float16*)(wsb + 67108864);
  _Float16* Wq16     = (_Float16*)(wsb + 69206016);

  const long long nK = (long long)B * P * H;   // 16.78M
  const long long nQ = (long long)B * Q * H;   // 8.39M
  const long long nW = (long long)H * H;       // 1.05M

  // 1. fused converts
  const int bK = (int)(nK / 1024), bQ = (int)(nQ / 1024), bW = (int)(nW / 1024);
  convert_all_kernel<<<bK + bQ + 2 * bW, 256, 0, stream>>>(
      k, k16, bK, q, q16, bQ, Wk, Wk16, bW, Wq, Wq16);

  const size_t LDSB = 65536;   // 64 KB dynamic LDS -> 2 blocks/CU
  // 2. fused projections: A = [k16 ; q16] contiguous [24576 x 1024].
  //    mt 0..127  -> relu(k16 @ Wk16^T) -> pkey16
  //    mt 128..191 -> relu(q16 @ Wq16^T) -> qkey16
  gemm_nt_f16_128<<<192 * 8, 256, LDSB, stream>>>(
      k16, Wk16, nullptr, pkey16, Wq16, qkey16, 128,
      H, H, 192, 8, 0LL, 0LL, 0LL, 1);
  // 3. scores = pkey16 @ qkey16^T (batched) -> alphas slice fp32
  gemm_nt_f16_128<<<16 * 8 * B, 256, LDSB, stream>>>(
      pkey16, qkey16, alphas, nullptr, qkey16, nullptr, 1 << 28,
      Q, H, 16, 8, (long long)P * H, (long long)Q * H, (long long)P * Q, 0);
  // 4. qT16 = q^T fp16 (overwrites q16; q16 dead after step 2)
  transpose_f16_kernel<<<dim3(Q / 64, H / 64, B), 256, 0, stream>>>(q, qT16, Q, H);
  // 5. softmax in place + fp16 copy (overwrites k16)
  softmax_rows_kernel<<<B * P, 256, 0, stream>>>(alphas, alphas16, qmask, Q, P);
  // 6. ctx = alphas16 @ qT16^T (batched NT) -> d_out base
  gemm_nt_f16_128<<<16 * 8 * B, 256, LDSB, stream>>>(
      alphas16, qT16, ctx, nullptr, qT16, nullptr, 1 << 28,
      H, Q, 16, 8, (long long)P * Q, (long long)H * Q, (long long)P * H, 0);
}

// Round 5
// 374.909 us; speedup vs baseline: 1.1771x; 1.0138x over previous
//
#include <hip/hip_runtime.h>
#include <hip/hip_bf16.h>
#include <math.h>

// B=8, P=2048, Q=1024, H=1024
// 1. convert k,q,Wk,Wq fp32 -> fp16 (single fused launch)
// 2. fused proj: pkey16 = relu(k @ Wk^T), qkey16 = relu(q @ Wq^T) in ONE
//    launch (k16/q16 contiguous in ws -> one [24576,1024] A; mt-split picks
//    weight + dest). pkey16 parked in d_out ctx region.
// 3. scores = pkey @ qkey^T    MFMA f16, fp32 -> alphas slice of d_out
// 4. qT16 = transpose(q) fp16
// 5. softmax rows in place + fp16 alphas copy
// 6. ctx = alphas16 @ qT16^T   MFMA f16, fp32 -> d_out base
//
// GEMM: 128x128 tile, BK=64, 256 thr = 4 waves (2x2), per-wave 64x64
// (acc[4][4]). 2 LDS buffers x 32KB = 64KB -> 2 blocks/CU.
//
// R5 CHANGE (single variable vs R4): tile decode is NT-FASTEST.
//   R4's M-fastest decode + XCD chunking made EVERY XCD stream the ENTIRE
//   A matrix (A re-read Ntiles x = ~1.4 GB beyond-L2 traffic across the 3
//   GEMMs); the vmcnt waits were feed-bound on L3, which is why R1-R4's
//   schedule rewrites all landed at ~400 TF.
//   NT-fastest + chunking: XCD j covers a contiguous mt range sweeping all
//   nt -> A-panels read ONCE (2 co-resident blocks/CU share the same
//   A-panel -> L1/L2 hits), B matrix (weights 2MB / per-batch panel 2MB)
//   L2-RESIDENT per XCD after the first mt sweep. Per-XCD footprint ~4MB
//   = L2 size. Beyond-L2 traffic ~1.4GB -> ~165MB.
// Schedule per K-tile t (unchanged from R3/R4, verified):
//   STAGE(t+1) [8 x global_load_lds x16B] -> s_waitcnt vmcnt(8) ->
//   s_barrier -> 2 phases {ds_read subtile -> 16 MFMA, setprio(1)} ->
//   lgkmcnt(0) -> s_barrier.
// LDS XOR swizzle (both sides; global_load_lds forces linear LDS dest):
//   BK=64 rows are 128B (= 0 mod banks). Physical 16B-slot = logical ^
//   (row&7); stage thread fetches pre-swizzled global col, reader XORs.

typedef _Float16 v8h __attribute__((ext_vector_type(8)));
typedef _Float16 v4h __attribute__((ext_vector_type(4)));
typedef float v4f __attribute__((ext_vector_type(4)));

#define AS1C(p) ((const __attribute__((address_space(1))) void*)(p))
#define AS3(p)  ((__attribute__((address_space(3))) void*)(p))

// ---------------------------------------------------------------------------
// NT MFMA GEMM: C[m,n] = sum_k A[m,k]*B[n,k], A:[M,K] B:[N,K] row-major f16.
// Grid multiple of 8 (XCD swizzle); tiles 128x128, K%64==0, K>=128.
// mt >= mtSplit switches to {B2, Ch2} with re-based output row (A stays
// contiguous) -- used to fuse the two relu-projections.
__global__ __launch_bounds__(256) void gemm_nt_f16_128(
    const _Float16* __restrict__ A, const _Float16* __restrict__ B,
    float* __restrict__ Cf, _Float16* __restrict__ Ch,
    const _Float16* __restrict__ B2, _Float16* __restrict__ Ch2, int mtSplit,
    int N, int K, int Mtiles, int Ntiles,
    long long sA, long long sB, long long sC, int relu)
{
  extern __shared__ _Float16 lds[];   // 2 bufs x (A 8192 elems | B 8192 elems)

  // XCD-aware swizzle (nwg % 8 == 0 for all our grids), then NT-FASTEST
  // decode: XCD j owns a contiguous mt range, sweeping all nt per mt.
  const int nwg = gridDim.x;
  const int cpx = nwg >> 3;
  const int bid = (blockIdx.x & 7) * cpx + (blockIdx.x >> 3);
  const int nt  = bid % Ntiles;
  const int mt  = (bid / Ntiles) % Mtiles;
  const int bz  = bid / (Mtiles * Ntiles);

  A += (long long)bz * sA;

  const _Float16* Bp = B;
  _Float16* Chp = Ch;
  int m0c = mt * 128;                 // output row base
  if (mt >= mtSplit) { Bp = B2; Chp = Ch2; m0c = (mt - mtSplit) * 128; }
  Bp += (long long)bz * sB;

  const int m0g = mt * 128;           // A row base (contiguous across split)
  const int n0  = nt * 128;
  const int t   = threadIdx.x;        // 0..255
  const int l   = t & 63;
  const int w   = t >> 6;             // 0..3
  const int wm  = (w >> 1) * 64;      // wave m offset: 0 or 64
  const int wn  = (w & 1) * 64;       // wave n offset: 0 or 64
  const int fr  = l & 15;
  const int fq  = l >> 4;
  const int r3  = fr & 7;
  // swizzled 16B-slot (in fp16 elems, *8) for kh=0 and kh=1 fragment reads
  const int sa0 = (fq ^ r3) * 8;
  const int sa1 = ((4 + fq) ^ r3) * 8;

  // Staging: 8 insts x 256 thr x 16B; per buffer 32KB (A 16KB + B 16KB).
  // Each inst covers 32 rows x 128B. Thread t: row-in-chunk = t>>3,
  // phys slot = t&7, pre-swizzled global col = ((t&7)^(row&7))*8.
  const int trow = t >> 3;                       // 0..31
  const int tswz = ((t & 7) ^ (trow & 7)) * 8;   // fp16 elems

  const _Float16* Ast = A  + (long long)(m0g + trow) * K + tswz;
  const _Float16* Bst = Bp + (long long)(n0  + trow) * K + tswz;

  v4f acc[4][4];
#pragma unroll
  for (int i = 0; i < 4; ++i)
#pragma unroll
    for (int j = 0; j < 4; ++j)
      acc[i][j] = (v4f){0.f, 0.f, 0.f, 0.f};

  const int NT = K >> 6;            // K-tiles of 64

#define STAGE(kt) do {                                                                   \
    _Float16* s_ = lds + (((kt) & 1) << 14);                                             \
    const long long ko_ = (long long)((kt) << 6);                                        \
    __builtin_amdgcn_global_load_lds(AS1C(Ast + ko_),               AS3(s_ +        t * 8), 16, 0, 0); \
    __builtin_amdgcn_global_load_lds(AS1C(Ast + 32LL * K + ko_),    AS3(s_ + 2048 + t * 8), 16, 0, 0); \
    __builtin_amdgcn_global_load_lds(AS1C(Ast + 64LL * K + ko_),    AS3(s_ + 4096 + t * 8), 16, 0, 0); \
    __builtin_amdgcn_global_load_lds(AS1C(Ast + 96LL * K + ko_),    AS3(s_ + 6144 + t * 8), 16, 0, 0); \
    __builtin_amdgcn_global_load_lds(AS1C(Bst + ko_),               AS3(s_ + 8192 + t * 8), 16, 0, 0); \
    __builtin_amdgcn_global_load_lds(AS1C(Bst + 32LL * K + ko_),    AS3(s_ + 10240 + t * 8), 16, 0, 0); \
    __builtin_amdgcn_global_load_lds(AS1C(Bst + 64LL * K + ko_),    AS3(s_ + 12288 + t * 8), 16, 0, 0); \
    __builtin_amdgcn_global_load_lds(AS1C(Bst + 96LL * K + ko_),    AS3(s_ + 14336 + t * 8), 16, 0, 0); \
  } while (0)

  STAGE(0);   // prologue: tile 0 in flight (8 loads)

  for (int kt = 0; kt < NT; ++kt) {
    if (kt + 1 < NT) {
      STAGE(kt + 1);   // buffer (kt+1)&1, freed by END barrier of iter kt-1
      asm volatile("s_waitcnt vmcnt(8)" ::: "memory");   // tile kt landed
    } else {
      asm volatile("s_waitcnt vmcnt(0)" ::: "memory");
    }
    __builtin_amdgcn_sched_barrier(0);
    __builtin_amdgcn_s_barrier();        // tile kt visible to all waves
    asm volatile("" ::: "memory");

    const _Float16* Ab = lds + ((kt & 1) << 14);
    const _Float16* Bb = Ab + 8192;

    v8h a0[4], a1[4], b0[4], b1[4];

    // P0: a rows i0-3 (both kh) + b cols j0-1 (both kh) -> 16 MFMA
#pragma unroll
    for (int i = 0; i < 4; ++i) {
      a0[i] = *(const v8h*)&Ab[(wm + i * 16 + fr) * 64 + sa0];
      a1[i] = *(const v8h*)&Ab[(wm + i * 16 + fr) * 64 + sa1];
    }
#pragma unroll
    for (int j = 0; j < 2; ++j) {
      b0[j] = *(const v8h*)&Bb[(wn + j * 16 + fr) * 64 + sa0];
      b1[j] = *(const v8h*)&Bb[(wn + j * 16 + fr) * 64 + sa1];
    }
    __builtin_amdgcn_s_setprio(1);
#pragma unroll
    for (int i = 0; i < 4; ++i)
#pragma unroll
      for (int j = 0; j < 2; ++j) {
        acc[i][j] = __builtin_amdgcn_mfma_f32_16x16x32_f16(a0[i], b0[j], acc[i][j], 0, 0, 0);
        acc[i][j] = __builtin_amdgcn_mfma_f32_16x16x32_f16(a1[i], b1[j], acc[i][j], 0, 0, 0);
      }
    __builtin_amdgcn_s_setprio(0);

    // P1: b cols j2-3 -> 16 MFMA
#pragma unroll
    for (int j = 2; j < 4; ++j) {
      b0[j] = *(const v8h*)&Bb[(wn + j * 16 + fr) * 64 + sa0];
      b1[j] = *(const v8h*)&Bb[(wn + j * 16 + fr) * 64 + sa1];
    }
    __builtin_amdgcn_s_setprio(1);
#pragma unroll
    for (int i = 0; i < 4; ++i)
#pragma unroll
      for (int j = 2; j < 4; ++j) {
        acc[i][j] = __builtin_amdgcn_mfma_f32_16x16x32_f16(a0[i], b0[j], acc[i][j], 0, 0, 0);
        acc[i][j] = __builtin_amdgcn_mfma_f32_16x16x32_f16(a1[i], b1[j], acc[i][j], 0, 0, 0);
      }
    __builtin_amdgcn_s_setprio(0);

    // All own ds_reads of buffer kt done before signaling; after this barrier
    // every wave finished reading buffer kt -> STAGE(kt+2) may overwrite.
    asm volatile("s_waitcnt lgkmcnt(0)" ::: "memory");
    __builtin_amdgcn_sched_barrier(0);
    __builtin_amdgcn_s_barrier();
  }
#undef STAGE

  float* Cfb = Cf ? Cf + (long long)bz * sC : nullptr;
  _Float16* Chb = Chp ? Chp + (long long)bz * sC : nullptr;
#pragma unroll
  for (int i = 0; i < 4; ++i) {
#pragma unroll
    for (int j = 0; j < 4; ++j) {
#pragma unroll
      for (int r = 0; r < 4; ++r) {
        const int row = m0c + wm + i * 16 + fq * 4 + r;
        const int col = n0 + wn + j * 16 + fr;
        float v = acc[i][j][r];
        if (relu) v = fmaxf(v, 0.f);
        if (Cfb) Cfb[(long long)row * N + col] = v;
        if (Chb) Chb[(long long)row * N + col] = (_Float16)v;
      }
    }
  }
}

// ---------------------------------------------------------------------------
// Fused fp32->fp16 conversion of all four inputs in one launch.
// Each block handles 1024 elements of one of the arrays.
__global__ __launch_bounds__(256) void convert_all_kernel(
    const float* __restrict__ s0, _Float16* __restrict__ d0, int b0,  // k
    const float* __restrict__ s1, _Float16* __restrict__ d1, int b1,  // q
    const float* __restrict__ s2, _Float16* __restrict__ d2, int b2,  // Wk
    const float* __restrict__ s3, _Float16* __restrict__ d3)          // Wq
{
  int blk = blockIdx.x;
  const float* src;
  _Float16* dst;
  if (blk < b0)           { src = s0; dst = d0; }
  else if (blk < b0 + b1) { src = s1; dst = d1; blk -= b0; }
  else if (blk < b0 + b1 + b2) { src = s2; dst = d2; blk -= b0 + b1; }
  else                    { src = s3; dst = d3; blk -= b0 + b1 + b2; }
  const long long i = ((long long)blk * 256 + threadIdx.x) * 4;
  const float4 v = *(const float4*)(src + i);
  v4h o = {(_Float16)v.x, (_Float16)v.y, (_Float16)v.z, (_Float16)v.w};
  *(v4h*)(dst + i) = o;
}

// q [B,Q,H] fp32 -> qT [B,H,Q] fp16, 64x64 tiles
__global__ __launch_bounds__(256) void transpose_f16_kernel(
    const float* __restrict__ q, _Float16* __restrict__ qT, int Q, int H)
{
  __shared__ float tile[64][65];
  const float* qb = q + (long long)blockIdx.z * Q * H;
  _Float16* qTb = qT + (long long)blockIdx.z * H * Q;
  const int q0 = blockIdx.x * 64, h0 = blockIdx.y * 64;
  const int t = threadIdx.x;
  const int tr = t >> 4, tc = (t & 15) << 2;
#pragma unroll
  for (int i = 0; i < 4; ++i) {
    const float4 v = *(const float4*)(qb + (long long)(q0 + tr + i * 16) * H + h0 + tc);
    tile[tr + i * 16][tc + 0] = v.x;
    tile[tr + i * 16][tc + 1] = v.y;
    tile[tr + i * 16][tc + 2] = v.z;
    tile[tr + i * 16][tc + 3] = v.w;
  }
  __syncthreads();
#pragma unroll
  for (int i = 0; i < 4; ++i) {
    const int hl = tr + i * 16;
    const int ql = tc;
    v4h o = {(_Float16)tile[ql + 0][hl], (_Float16)tile[ql + 1][hl],
             (_Float16)tile[ql + 2][hl], (_Float16)tile[ql + 3][hl]};
    *(v4h*)(qTb + (long long)(h0 + hl) * Q + q0 + ql) = o;
  }
}

// softmax rows of S [B*P, Q] fp32 in place; also write fp16 copy
__global__ __launch_bounds__(256) void softmax_rows_kernel(
    float* __restrict__ S, _Float16* __restrict__ S16,
    const unsigned char* __restrict__ qmask, int Q, int P)
{
  const long long row = blockIdx.x;       // b*P + p
  const int b = (int)(row / P);
  float* s = S + row * (long long)Q;
  const unsigned char* msk = qmask + (long long)b * Q;
  const int t = threadIdx.x;
  float4 v = *(const float4*)(s + (t << 2));
  float vals[4] = {v.x, v.y, v.z, v.w};
#pragma unroll
  for (int j = 0; j < 4; ++j)
    if (msk[(t << 2) + j]) vals[j] = -INFINITY;

  __shared__ float red[8];
  const int wid = t >> 6, lid = t & 63;

  float mx = fmaxf(fmaxf(vals[0], vals[1]), fmaxf(vals[2], vals[3]));
#pragma unroll
  for (int o = 32; o > 0; o >>= 1) mx = fmaxf(mx, __shfl_xor(mx, o, 64));
  if (lid == 0) red[wid] = mx;
  __syncthreads();
  mx = fmaxf(fmaxf(red[0], red[1]), fmaxf(red[2], red[3]));

  float e[4];
  float sum = 0.f;
#pragma unroll
  for (int j = 0; j < 4; ++j) { e[j] = __expf(vals[j] - mx); sum += e[j]; }
#pragma unroll
  for (int o = 32; o > 0; o >>= 1) sum += __shfl_xor(sum, o, 64);
  __syncthreads();
  if (lid == 0) red[4 + wid] = sum;
  __syncthreads();
  sum = red[4] + red[5] + red[6] + red[7];
  const float inv = 1.f / sum;

  float4 o;
  o.x = e[0] * inv; o.y = e[1] * inv; o.z = e[2] * inv; o.w = e[3] * inv;
  *(float4*)(s + (t << 2)) = o;
  v4h oh = {(_Float16)o.x, (_Float16)o.y, (_Float16)o.z, (_Float16)o.w};
  *(v4h*)(S16 + row * (long long)Q + (t << 2)) = oh;
}

// ---------------------------------------------------------------------------
extern "C" void kernel_launch(void* const* d_in, const int* in_sizes, int n_in,
                              void* d_out, int out_size, void* d_ws, size_t ws_size,
                              hipStream_t stream)
{
  const int B = 8, P = 2048, Q = 1024, H = 1024;
  const float* k  = (const float*)d_in[0];
  const float* q  = (const float*)d_in[1];
  const unsigned char* qmask = (const unsigned char*)d_in[2];
  const float* Wk = (const float*)d_in[3];
  const float* Wq = (const float*)d_in[4];

  float* ctx    = (float*)d_out;                  // [B,P,H] fp32
  float* alphas = ctx + (size_t)B * P * H;        // [B,P,Q] fp32

  _Float16* pkey16 = (_Float16*)d_out;            // parked in ctx region

  char* wsb = (char*)d_ws;
  _Float16* qkey16   = (_Float16*)(wsb);                        // 16.78 MB
  _Float16* k16      = (_Float16*)(wsb + 16777216);             // 33.55 MB
  _Float16* alphas16 = k16;                                     // k16 dead after proj
  _Float16* q16      = (_Float16*)(wsb + 16777216 + 33554432);  // 16.78 MB, CONTIGUOUS after k16
  _Float16* qT16     = q16;                                     // q16 dead after proj
  _Float16* Wk16     = (_Float16*)(wsb + 67108864);
  _Float16* Wq16     = (_Float16*)(wsb + 69206016);

  const long long nK = (long long)B * P * H;   // 16.78M
  const long long nQ = (long long)B * Q * H;   // 8.39M
  const long long nW = (long long)H * H;       // 1.05M

  // 1. fused converts
  const int bK = (int)(nK / 1024), bQ = (int)(nQ / 1024), bW = (int)(nW / 1024);
  convert_all_kernel<<<bK + bQ + 2 * bW, 256, 0, stream>>>(
      k, k16, bK, q, q16, bQ, Wk, Wk16, bW, Wq, Wq16);

  const size_t LDSB = 65536;   // 64 KB dynamic LDS -> 2 blocks/CU
  // 2. fused projections: A = [k16 ; q16] contiguous [24576 x 1024].
  //    mt 0..127  -> relu(k16 @ Wk16^T) -> pkey16
  //    mt 128..191 -> relu(q16 @ Wq16^T) -> qkey16
  gemm_nt_f16_128<<<192 * 8, 256, LDSB, stream>>>(
      k16, Wk16, nullptr, pkey16, Wq16, qkey16, 128,
      H, H, 192, 8, 0LL, 0LL, 0LL, 1);
  // 3. scores = pkey16 @ qkey16^T (batched) -> alphas slice fp32
  gemm_nt_f16_128<<<16 * 8 * B, 256, LDSB, stream>>>(
      pkey16, qkey16, alphas, nullptr, qkey16, nullptr, 1 << 28,
      Q, H, 16, 8, (long long)P * H, (long long)Q * H, (long long)P * Q, 0);
  // 4. qT16 = q^T fp16 (overwrites q16; q16 dead after step 2)
  transpose_f16_kernel<<<dim3(Q / 64, H / 64, B), 256, 0, stream>>>(q, qT16, Q, H);
  // 5. softmax in place + fp16 copy (overwrites k16)
  softmax_rows_kernel<<<B * P, 256, 0, stream>>>(alphas, alphas16, qmask, Q, P);
  // 6. ctx = alphas16 @ qT16^T (batched NT) -> d_out base
  gemm_nt_f16_128<<<16 * 8 * B, 256, LDSB, stream>>>(
      alphas16, qT16, ctx, nullptr, qT16, nullptr, 1 << 28,
      H, Q, 16, 8, (long long)P * Q, (long long)H * Q, (long long)P * H, 0);
}